// Round 11
// baseline (405.351 us; speedup 1.0000x reference)
//
#include <hip/hip_runtime.h>

#define NPATH  2048
#define DIM    64
#define NSTEPS 500
#define PPW    16   // paths per wave-tile
#define RD     8    // dW ring depth (LDS slots)

typedef __attribute__((ext_vector_type(8))) short bf16x8;
typedef __attribute__((ext_vector_type(4))) float f32x4;
typedef __attribute__((ext_vector_type(4))) unsigned int u32x4;

union FragU { bf16x8 v; unsigned int u[4]; u32x4 q; };

__device__ __forceinline__ unsigned int pk_bf16(float lo, float hi) {
    unsigned int r;
    asm("v_cvt_pk_bf16_f32 %0, %1, %2" : "=v"(r) : "v"(lo), "v"(hi));
    return r;
}

// async HBM->LDS, 16B per lane; LDS dest = uniform base + lane*16
__device__ __forceinline__ void gl_lds16(const float* src, void* dst) {
    __builtin_amdgcn_global_load_lds(
        (const __attribute__((address_space(1))) void*)src,
        (__attribute__((address_space(3))) void*)dst, 16, 0, 0);
}

#define MFMA __builtin_amdgcn_mfma_f32_16x16x32_bf16
#define VMW_(N) asm volatile("s_waitcnt vmcnt(" #N ")" ::: "memory")
#define VMW(N)  VMW_(N)

// One wave per 16-path tile; r10's sigma-permuted register recurrence
// (MFMA C-output layout == next step's B-fragment layout, closed by 8
// in-register cvt_pk), but with NO large long-lived register arrays
// (r3-r10 lesson: the allocator spills them to scratch no matter what):
//  - matrix fragments live in LDS (16 KB, read per step, transient regs)
//  - dW ring lives in LDS, filled by global_load_lds DMA (0 VGPRs),
//    depth 8, counted vmcnt(56) per step (never drained in the loop)
// Persistent regs ~70: state (16), xf (8), biases (32), pointers.
__attribute__((amdgpu_waves_per_eu(1, 1)))
__global__ __launch_bounds__(64) void sde_ring_kernel(
    const float* __restrict__ x0,
    const float* __restrict__ dW,
    const float* __restrict__ drift,
    const float* __restrict__ drift_bias,
    const float* __restrict__ diffusion,
    const float* __restrict__ diffusion_bias,
    const float* __restrict__ ts,
    float* __restrict__ out)
{
    __shared__ __align__(16) u32x4 mfL[16][64];          // 16 KB matrix frags
    __shared__ __align__(16) float ring[RD][PPW * DIM];  // 32 KB dW ring
    __shared__ float2 dtp[NSTEPS + 1];                   // 4 KB {dt, sqrt(dt)}

    const int lane = threadIdx.x;        // 0..63
    const int c    = lane & 15;          // path within tile / MFMA col
    const int h    = lane >> 4;          // k-slot group
    const int o8h  = 8 * h;
    const int p    = blockIdx.x * PPW + c;

    for (int i = lane; i < NSTEPS; i += 64) {
        const float d = ts[i + 1] - ts[i];              // f32-exact vs reference
        dtp[i] = make_float2(d, sqrtf(d));
    }
    if (lane == 0) dtp[NSTEPS] = make_float2(0.f, 0.f);

    static const int oo[4] = {0, 4, 32, 36};            // dim offset of block beta

    // ---- matrix fragments (sigma-permuted, r9-verified) -> LDS, once ----
#pragma unroll
    for (int mat = 0; mat < 2; ++mat) {
        const float* __restrict__ M = mat ? diffusion : drift;
#pragma unroll
        for (int b = 0; b < 4; ++b) {
            const int row = 32 * (b >> 1) + 8 * (c >> 2) + 4 * (b & 1) + (c & 3);
            const float* Mr = M + row * DIM + o8h;
#pragma unroll
            for (int kk = 0; kk < 2; ++kk) {
                const f32x4 lo = *(const f32x4*)(Mr + 32 * kk);
                const f32x4 hi = *(const f32x4*)(Mr + 32 * kk + 4);
                FragU f;
                f.u[0] = pk_bf16(lo[0], lo[1]); f.u[1] = pk_bf16(lo[2], lo[3]);
                f.u[2] = pk_bf16(hi[0], hi[1]); f.u[3] = pk_bf16(hi[2], hi[3]);
                mfL[mat * 8 + b * 2 + kk][lane] = f.q;
            }
        }
    }

    // biases (C-init vectors): small enough to stay resident
    f32x4 bA[4], bC[4];
#pragma unroll
    for (int b = 0; b < 4; ++b) {
        bA[b] = *(const f32x4*)(drift_bias     + o8h + oo[b]);
        bC[b] = *(const f32x4*)(diffusion_bias + o8h + oo[b]);
    }

    // ---- state init ----
    const float* pdw  = dW  + (size_t)p * NSTEPS * DIM + o8h;
    float*       pout = out + (size_t)p * (NSTEPS + 1) * DIM + o8h;
    f32x4 xs_[4];
#pragma unroll
    for (int b = 0; b < 4; ++b) {
        xs_[b] = *(const f32x4*)(x0 + p * DIM + o8h + oo[b]);
        *(f32x4*)(pout + oo[b]) = xs_[b];               // ys[:,0,:]
    }
    pout += DIM;

    FragU xf0, xf1;                                     // state B-fragments
    xf0.u[0] = pk_bf16(xs_[0][0], xs_[0][1]); xf0.u[1] = pk_bf16(xs_[0][2], xs_[0][3]);
    xf0.u[2] = pk_bf16(xs_[1][0], xs_[1][1]); xf0.u[3] = pk_bf16(xs_[1][2], xs_[1][3]);
    xf1.u[0] = pk_bf16(xs_[2][0], xs_[2][1]); xf1.u[1] = pk_bf16(xs_[2][2], xs_[2][3]);
    xf1.u[2] = pk_bf16(xs_[3][0], xs_[3][1]); xf1.u[3] = pk_bf16(xs_[3][2], xs_[3][3]);

    // ---- prologue: DMA-fill ring slots 0..7 (steps 0..7), then drain once ----
#pragma unroll
    for (int s = 0; s < RD; ++s)
#pragma unroll
        for (int b = 0; b < 4; ++b)
            gl_lds16(pdw + s * DIM + oo[b], &ring[s][b * 256]);

    const float* pdwp   = pdw + RD * DIM;               // prefetch src (step 8)
    const float* pdwend = pdw + (NSTEPS - 1) * DIM;     // clamp (step 499)
    const float2* pdt   = &dtp[0];

    VMW(0);              // one-time drain: ring slots 0..7 + all init loads done
    __syncthreads();

    // Per step: counted vmcnt(56) = 8 vmem/step x 7 steps in flight (4 stores
    // + 4 DMA per step, sched_barrier(0) pins the per-step vmem count).
    // Consume slot K, then refill it for step S+8 (program order after the
    // lgkm-waited R use guarantees read-before-DMA-overwrite).
#define STEP(K)                                                               \
    {                                                                         \
        VMW(56);                                                              \
        const float2 dtc = *pdt++;                                            \
        f32x4 Rr[4];                                                          \
        _Pragma("unroll")                                                     \
        for (int b = 0; b < 4; ++b)                                           \
            Rr[b] = *(const f32x4*)&ring[K][b * 256 + 4 * lane];              \
        _Pragma("unroll")                                                     \
        for (int b = 0; b < 4; ++b) {                                         \
            FragU fa0, fa1, fc0, fc1;                                         \
            fa0.q = mfL[2 * b + 0][lane];                                     \
            fa1.q = mfL[2 * b + 1][lane];                                     \
            fc0.q = mfL[8 + 2 * b + 0][lane];                                 \
            fc1.q = mfL[8 + 2 * b + 1][lane];                                 \
            f32x4 ad = MFMA(fa0.v, xf0.v, bA[b], 0, 0, 0);                    \
            ad       = MFMA(fa1.v, xf1.v, ad,    0, 0, 0);                    \
            f32x4 ci = MFMA(fc0.v, xf0.v, bC[b], 0, 0, 0);                    \
            ci       = MFMA(fc1.v, xf1.v, ci,    0, 0, 0);                    \
            f32x4 xn;                                                         \
            _Pragma("unroll")                                                 \
            for (int j = 0; j < 4; ++j)                                       \
                xn[j] = fmaf(dtc.x, ad[j], xs_[b][j])                         \
                        + ci[j] * (dtc.y * Rr[b][j]);                         \
            xs_[b] = xn;                                                      \
            *(f32x4*)(pout + oo[b]) = xn;                                     \
        }                                                                     \
        xf0.u[0] = pk_bf16(xs_[0][0], xs_[0][1]);                             \
        xf0.u[1] = pk_bf16(xs_[0][2], xs_[0][3]);                             \
        xf0.u[2] = pk_bf16(xs_[1][0], xs_[1][1]);                             \
        xf0.u[3] = pk_bf16(xs_[1][2], xs_[1][3]);                             \
        xf1.u[0] = pk_bf16(xs_[2][0], xs_[2][1]);                             \
        xf1.u[1] = pk_bf16(xs_[2][2], xs_[2][3]);                             \
        xf1.u[2] = pk_bf16(xs_[3][0], xs_[3][1]);                             \
        xf1.u[3] = pk_bf16(xs_[3][2], xs_[3][3]);                             \
        {                                                                     \
            const float* pf = (pdwp <= pdwend) ? pdwp : pdwend;               \
            gl_lds16(pf + 0,  &ring[K][0]);                                   \
            gl_lds16(pf + 4,  &ring[K][256]);                                 \
            gl_lds16(pf + 32, &ring[K][512]);                                 \
            gl_lds16(pf + 36, &ring[K][768]);                                 \
        }                                                                     \
        pdwp += DIM;                                                          \
        pout += DIM;                                                          \
        __builtin_amdgcn_sched_barrier(0);                                    \
    }

    // 62 x 8 = 496 steps, then 4 more = 500
    for (int it = 0; it < 62; ++it) {
        STEP(0) STEP(1) STEP(2) STEP(3) STEP(4) STEP(5) STEP(6) STEP(7)
    }
    STEP(0) STEP(1) STEP(2) STEP(3)
#undef STEP
}

extern "C" void kernel_launch(void* const* d_in, const int* in_sizes, int n_in,
                              void* d_out, int out_size, void* d_ws, size_t ws_size,
                              hipStream_t stream) {
    const float* x0             = (const float*)d_in[0];
    const float* dW             = (const float*)d_in[1];
    const float* drift          = (const float*)d_in[2];
    const float* drift_bias     = (const float*)d_in[3];
    const float* diffusion      = (const float*)d_in[4];
    const float* diffusion_bias = (const float*)d_in[5];
    const float* ts             = (const float*)d_in[6];
    float* out = (float*)d_out;

    dim3 grid(NPATH / PPW);   // 128 blocks = 128 independent wave-tiles
    dim3 block(64);           // one wave
    hipLaunchKernelGGL(sde_ring_kernel, grid, block, 0, stream,
                       x0, dW, drift, drift_bias, diffusion, diffusion_bias,
                       ts, out);
}

// Round 12
// 138.200 us; speedup vs baseline: 2.9331x; 2.9331x over previous
//
#include <hip/hip_runtime.h>

#define NPATH  2048
#define DIM    64
#define NSTEPS 500
#define PPW    16   // paths per tile (one block per tile, 4 waves)

typedef __attribute__((ext_vector_type(8))) short bf16x8;
typedef __attribute__((ext_vector_type(4))) float f32x4;

union FragU { bf16x8 v; unsigned int u[4]; uint4 q; };

__device__ __forceinline__ unsigned int pk_bf16(float lo, float hi) {
    unsigned int r;
    asm("v_cvt_pk_bf16_f32 %0, %1, %2" : "=v"(r) : "v"(lo), "v"(hi));
    return r;
}

#define MFMA __builtin_amdgcn_mfma_f32_16x16x32_bf16

// r8 structure (best verified: 151us), chain-shortened.
// One block = one 16-path tile, 4 waves; wave wn owns output dims
// [16wn,16wn+16). Matrix frags (4 x 16B) in VGPRs. State tile xt: bf16 in
// LDS, ping-pong, XOR-swizzled (0 bank conflicts measured). One raw barrier
// per step, lgkmcnt-only drain (dW ring never vmcnt-drained).
// Changes vs r8: independent MFMA pairs (C=bias / C=0 + VALU add,
// r10-verified numerics); ds_read issued at phase top with srw precompute
// and ring prefetch overlapped under its latency; ring depth 8;
// pointer-increment stores; launch_bounds(256,1) for register budget.
__global__ __launch_bounds__(256, 1) void sde_mfma_mw2_kernel(
    const float* __restrict__ x0,
    const float* __restrict__ dW,
    const float* __restrict__ drift,
    const float* __restrict__ drift_bias,
    const float* __restrict__ diffusion,
    const float* __restrict__ diffusion_bias,
    const float* __restrict__ ts,
    float* __restrict__ out)
{
    __shared__ __align__(16) unsigned short xt[2][PPW * DIM];  // bf16, swizzled
    __shared__ float2 dtp[NSTEPS + 1];

    const int tid   = threadIdx.x;
    const int wn    = tid >> 6;          // wave = output-dim quarter
    const int lane  = tid & 63;
    const int c     = lane & 15;
    const int h     = lane >> 4;
    const int pbase = blockIdx.x * PPW;
    const int mydim = 16 * wn + c;

    for (int i = tid; i < NSTEPS; i += 256) {
        const float d = ts[i + 1] - ts[i];          // f32-exact vs reference
        dtp[i] = make_float2(d, sqrtf(d));
    }
    if (tid == 0) dtp[NSTEPS] = make_float2(0.f, 0.f);

    // B-frags for this wave's quarter (r8-verified k-packing: lane (c,h)
    // holds M[mydim][32*kk + 8*h + e], e=0..7, matching the A-side packing)
    FragU bd0, bd1, bs0, bs1;
    {
        const float* Ar = drift     + mydim * DIM + 8 * h;
        const float* Cr = diffusion + mydim * DIM + 8 * h;
        float4 t;
        t = *(const float4*)(Ar +  0); bd0.u[0] = pk_bf16(t.x, t.y); bd0.u[1] = pk_bf16(t.z, t.w);
        t = *(const float4*)(Ar +  4); bd0.u[2] = pk_bf16(t.x, t.y); bd0.u[3] = pk_bf16(t.z, t.w);
        t = *(const float4*)(Ar + 32); bd1.u[0] = pk_bf16(t.x, t.y); bd1.u[1] = pk_bf16(t.z, t.w);
        t = *(const float4*)(Ar + 36); bd1.u[2] = pk_bf16(t.x, t.y); bd1.u[3] = pk_bf16(t.z, t.w);
        t = *(const float4*)(Cr +  0); bs0.u[0] = pk_bf16(t.x, t.y); bs0.u[1] = pk_bf16(t.z, t.w);
        t = *(const float4*)(Cr +  4); bs0.u[2] = pk_bf16(t.x, t.y); bs0.u[3] = pk_bf16(t.z, t.w);
        t = *(const float4*)(Cr + 32); bs1.u[0] = pk_bf16(t.x, t.y); bs1.u[1] = pk_bf16(t.z, t.w);
        t = *(const float4*)(Cr + 36); bs1.u[2] = pk_bf16(t.x, t.y); bs1.u[3] = pk_bf16(t.z, t.w);
    }
    const float bdr = drift_bias[mydim];
    const float bdi = diffusion_bias[mydim];
    const f32x4 cbA = {bdr, bdr, bdr, bdr};     // C-init: bias (k0 half)
    const f32x4 cbC = {bdi, bdi, bdi, bdi};
    const f32x4 cz  = {0.f, 0.f, 0.f, 0.f};    // C-init: zero (k1 half)

    // state (4 paths x this lane's dim), pointers, xt write offsets
    float xst[4];
    const float* dwq[4];
    float* op[4];
    unsigned int woff[4];
#pragma unroll
    for (int j = 0; j < 4; ++j) {
        const int pp = 4 * h + j;
        const int p  = pbase + pp;
        dwq[j] = dW  + (size_t)p * NSTEPS * DIM + mydim;
        op[j]  = out + (size_t)p * (NSTEPS + 1) * DIM + mydim;
        woff[j] = (unsigned)((pp * 32 + ((mydim >> 1) ^ ((pp & 7) << 2))) * 2 + (c & 1));
        const float v = x0[p * DIM + mydim];
        xst[j] = v;
        __builtin_nontemporal_store(v, op[j]);          // ys[:,0,:]
        op[j] += DIM;                                   // -> row 1
        xt[0][woff[j]] = (unsigned short)pk_bf16(v, v); // x tile for step 0
    }

    // step-invariant read offsets (uint4 granularity; swizzle folded in)
    const int ra0 = c * 8 + (h ^ (c & 7));          // dims 8h+0..7   of path c
    const int ra1 = c * 8 + ((4 + h) ^ (c & 7));    // dims 32+8h+0..7
    const uint4* xr0 = (const uint4*)xt[0];
    const uint4* xr1 = (const uint4*)xt[1];
    unsigned short* xw0 = xt[0];
    unsigned short* xw1 = xt[1];

    // dW prefetch ring, depth 8 (named rings, static indices only)
    float R0[4], R1[4], R2[4], R3[4], R4[4], R5[4], R6[4], R7[4];
#pragma unroll
    for (int j = 0; j < 4; ++j) {
        R0[j] = dwq[j][0 * DIM]; R1[j] = dwq[j][1 * DIM];
        R2[j] = dwq[j][2 * DIM]; R3[j] = dwq[j][3 * DIM];
        R4[j] = dwq[j][4 * DIM]; R5[j] = dwq[j][5 * DIM];
        R6[j] = dwq[j][6 * DIM]; R7[j] = dwq[j][7 * DIM];
        dwq[j] += 8 * DIM;               // now points at step s+8
    }

    __syncthreads();                     // one-time full sync (xt[0], dtp ready)

    float2 dts = dtp[0];                 // {dt, sdt} current step

    // Phase layout: ds_read first (chain head); srw precompute + ring
    // prefetch issue under the read latency; 4 independent MFMAs; update;
    // NT store + bf16 xt write; lgkm-only drain; raw barrier.
#define STEP(S, R, PF, KOFF, XR, XW)                                          \
    {                                                                         \
        FragU a0, a1;                                                         \
        a0.q = XR[ra0];                                                       \
        a1.q = XR[ra1];                                                       \
        const float srw0 = dts.y * R[0];  /* consume ring before overwrite */ \
        const float srw1 = dts.y * R[1];                                      \
        const float srw2 = dts.y * R[2];                                      \
        const float srw3 = dts.y * R[3];                                      \
        if (PF) {                                                             \
            R[0] = dwq[0][(KOFF) * DIM];                                      \
            R[1] = dwq[1][(KOFF) * DIM];                                      \
            R[2] = dwq[2][(KOFF) * DIM];                                      \
            R[3] = dwq[3][(KOFF) * DIM];                                      \
        }                                                                     \
        const float2 dtn = dtp[(S) + 1];                                      \
        const f32x4 adA = MFMA(a0.v, bd0.v, cbA, 0, 0, 0);                    \
        const f32x4 adB = MFMA(a1.v, bd1.v, cz,  0, 0, 0);                    \
        const f32x4 ciA = MFMA(a0.v, bs0.v, cbC, 0, 0, 0);                    \
        const f32x4 ciB = MFMA(a1.v, bs1.v, cz,  0, 0, 0);                    \
        const float srw[4] = {srw0, srw1, srw2, srw3};                        \
        _Pragma("unroll")                                                     \
        for (int j = 0; j < 4; ++j) {                                         \
            const float ad = adA[j] + adB[j];                                 \
            const float ci = ciA[j] + ciB[j];                                 \
            const float xn = fmaf(dts.x, ad, xst[j]) + ci * srw[j];           \
            xst[j] = xn;                                                      \
            __builtin_nontemporal_store(xn, op[j]);                           \
            op[j] += DIM;                                                     \
            XW[woff[j]] = (unsigned short)pk_bf16(xn, xn);                    \
        }                                                                     \
        dts = dtn;                                                            \
        asm volatile("s_waitcnt lgkmcnt(0)" ::: "memory");                    \
        __builtin_amdgcn_s_barrier();                                         \
        __builtin_amdgcn_sched_barrier(0);                                    \
    }

    // main loop: 61 x 8 = steps 0..487, prefetching steps 8..495
    for (int it = 0; it < 61; ++it) {
        const int s = it * 8;
        STEP(s + 0, R0, 1, 0, xr0, xw1)
        STEP(s + 1, R1, 1, 1, xr1, xw0)
        STEP(s + 2, R2, 1, 2, xr0, xw1)
        STEP(s + 3, R3, 1, 3, xr1, xw0)
        STEP(s + 4, R4, 1, 4, xr0, xw1)
        STEP(s + 5, R5, 1, 5, xr1, xw0)
        STEP(s + 6, R6, 1, 6, xr0, xw1)
        STEP(s + 7, R7, 1, 7, xr1, xw0)
#pragma unroll
        for (int j = 0; j < 4; ++j) dwq[j] += 8 * DIM;
    }
    // tail 1: steps 488..495; prefetch only steps 496..499 (k<4)
    {
        STEP(488, R0, 1, 0, xr0, xw1)
        STEP(489, R1, 1, 1, xr1, xw0)
        STEP(490, R2, 1, 2, xr0, xw1)
        STEP(491, R3, 1, 3, xr1, xw0)
        STEP(492, R4, 0, 0, xr0, xw1)
        STEP(493, R5, 0, 0, xr1, xw0)
        STEP(494, R6, 0, 0, xr0, xw1)
        STEP(495, R7, 0, 0, xr1, xw0)
    }
    // tail 2: steps 496..499, no prefetch
    {
        STEP(496, R0, 0, 0, xr0, xw1)
        STEP(497, R1, 0, 0, xr1, xw0)
        STEP(498, R2, 0, 0, xr0, xw1)
        STEP(499, R3, 0, 0, xr1, xw0)
    }
#undef STEP
}

extern "C" void kernel_launch(void* const* d_in, const int* in_sizes, int n_in,
                              void* d_out, int out_size, void* d_ws, size_t ws_size,
                              hipStream_t stream) {
    const float* x0             = (const float*)d_in[0];
    const float* dW             = (const float*)d_in[1];
    const float* drift          = (const float*)d_in[2];
    const float* drift_bias     = (const float*)d_in[3];
    const float* diffusion      = (const float*)d_in[4];
    const float* diffusion_bias = (const float*)d_in[5];
    const float* ts             = (const float*)d_in[6];
    float* out = (float*)d_out;

    dim3 grid(NPATH / PPW);   // 128 blocks (one 16-path tile each)
    dim3 block(256);          // 4 waves
    hipLaunchKernelGGL(sde_mfma_mw2_kernel, grid, block, 0, stream,
                       x0, dW, drift, drift_bias, diffusion, diffusion_bias,
                       ts, out);
}